// Round 9
// baseline (380.926 us; speedup 1.0000x reference)
//
#include <hip/hip_runtime.h>
#include <stdint.h>
#include <stddef.h>

#define N_CHEM 200000
#define N_GENE 20000
#define N_EDGES 1000000
#define IN_D 128
#define HID_D 256
#define OUT_D 128
#define N_SEG (N_GENE + N_CHEM)          // 220000 concatenated segments

// ---- bucket decomposition of the segment space -----------------------------
#define NGB 313
#define NCB 391
#define NB  (NGB + NCB)                  // 704
#define EPB 4096                         // r4/r8-measured best
#define NBA ((2 * N_EDGES + EPB - 1) / EPB)   // 489 place blocks
#define CAP 8192                         // per-bucket capacity (exp<=3500)
#define DROPPED 0x80000000               // overflow sentinel (never hit)

typedef float nfloat4 __attribute__((ext_vector_type(4)));   // native vec for NT store
typedef __attribute__((ext_vector_type(8))) short bf16x8;    // 8 bf16 = 4 VGPRs
typedef __attribute__((ext_vector_type(4))) float f32x4;

__device__ inline unsigned bf16rne(float x) {
    unsigned u = __float_as_uint(x);
    return (u + 0x7FFFu + ((u >> 16) & 1u)) >> 16;
}

__device__ inline int bucket_of(int slot) {
    return (slot < N_GENE) ? (slot >> 6) : (NGB + ((slot - N_GENE) >> 9));
}
__device__ inline int bucket_slot0(int b) {
    return (b < NGB) ? (b << 6) : (N_GENE + ((b - NGB) << 9));
}

// ---------------- CSR build ------------------------------------------------
// Pass A (fused): scatter packed (local_slot<<18 | src) records into
// fixed-capacity bucket regions, LDS-ordered so global writes are coalesced
// runs. Blocks >= NBA do the independent f32->bf16 embed conversion.
// Measured: ~64us at 4 AND 5 blk/CU -> throughput-bound, not occupancy-bound.
// NOTE (r7): column-slicing gathers = 2x FETCH loss (128B HBM granule,
// blockIdx does not track XCDs). NOTE (r5): per-block __threadfence = 100us.

__global__ __launch_bounds__(256) void place_convert_kernel(
        const int* __restrict__ src_cg, const int* __restrict__ dst_cg,
        const int* __restrict__ src_gc, const int* __restrict__ dst_gc,
        int* __restrict__ bcur, unsigned* __restrict__ records,
        const float* __restrict__ conv_in, unsigned short* __restrict__ conv_out) {
    if ((int)blockIdx.x >= NBA) {
        int cb = blockIdx.x - NBA;
        const int tid = threadIdx.x;
        #pragma unroll
        for (int q = 0; q < 4; ++q) {
            int i = cb * 1024 + q * 256 + tid;
            if (i < N_CHEM * IN_D / 4) {
                float4 v = *(const float4*)&conv_in[(size_t)i * 4];
                uint2 w;
                w.x = bf16rne(v.x) | (bf16rne(v.y) << 16);
                w.y = bf16rne(v.z) | (bf16rne(v.w) << 16);
                *(uint2*)&conv_out[(size_t)i * 4] = w;
            }
        }
        return;
    }
    __shared__ unsigned stage_rec[EPB];        // 16 KB packed records
    __shared__ unsigned short stage_bkt[EPB];  // 8 KB bucket ids
    __shared__ int hist[NB];                   // counts -> dump offsets (reused)
    __shared__ int cursor[NB];                 // excl scan -> staging cursor
    __shared__ int tsum[256];
    const int tid = threadIdx.x;
    const int e0 = blockIdx.x * EPB;
    const int cnt_blk = min(EPB, 2 * N_EDGES - e0);

    for (int i = tid; i < NB; i += 256) hist[i] = 0;
    __syncthreads();

    int slotR[EPB / 256], srcR[EPB / 256];
    #pragma unroll
    for (int q = 0; q < EPB / 256; ++q) {
        int e = e0 + q * 256 + tid;
        int slot = -1, s = 0;
        if (e < N_EDGES)            { slot = dst_cg[e];                    s = src_cg[e]; }
        else if (e < 2 * N_EDGES)   { slot = N_GENE + dst_gc[e - N_EDGES]; s = src_gc[e - N_EDGES]; }
        slotR[q] = slot; srcR[q] = s;
        if (slot >= 0) atomicAdd(&hist[bucket_of(slot)], 1);
    }
    __syncthreads();

    const int b3 = tid * 3;
    int h0 = (b3     < NB) ? hist[b3]     : 0;
    int h1 = (b3 + 1 < NB) ? hist[b3 + 1] : 0;
    int h2 = (b3 + 2 < NB) ? hist[b3 + 2] : 0;
    int ts = h0 + h1 + h2;
    tsum[tid] = ts;
    __syncthreads();
    for (int off = 1; off < 256; off <<= 1) {
        int t = (tid >= off) ? tsum[tid - off] : 0;
        __syncthreads();
        tsum[tid] += t;
        __syncthreads();
    }
    int base = tsum[tid] - ts;
    if (b3     < NB) cursor[b3]     = base;
    if (b3 + 1 < NB) cursor[b3 + 1] = base + h0;
    if (b3 + 2 < NB) cursor[b3 + 2] = base + h0 + h1;
    __syncthreads();

    #pragma unroll
    for (int q = 0; q < EPB / 256; ++q) {
        int slot = slotR[q];
        if (slot >= 0) {
            int b = bucket_of(slot);
            int p = atomicAdd(&cursor[b], 1);
            stage_rec[p] = ((unsigned)(slot - bucket_slot0(b)) << 18) | (unsigned)srcR[q];
            stage_bkt[p] = (unsigned short)b;
        }
    }
    __syncthreads();

    for (int i = tid; i < NB; i += 256) {
        int n = hist[i];
        if (n) {
            int got = atomicAdd(&bcur[i], n);
            int excl_i = cursor[i] - n;          // cursor is now excl+n
            hist[i] = (got + n <= CAP) ? (i * CAP + got - excl_i) : (int)DROPPED;
        }
    }
    __syncthreads();

    for (int i = tid; i < cnt_blk; i += 256) {
        int d = hist[stage_bkt[i]];
        if (d != (int)DROPPED) records[i + d] = stage_rec[i];
    }
}

// Pass B: one block per bucket -> local histogram+scan -> istart/iend + esrc.
// esrc lives in the CAP-strided bucket regions (rbase = b*CAP), so no global
// prefix scan is needed -> the bucket_scan dispatch is eliminated.

__global__ __launch_bounds__(256) void bin_b_kernel(
        const unsigned* __restrict__ records, const int* __restrict__ bcur,
        int* __restrict__ istart, int* __restrict__ iend, int* __restrict__ esrc) {
    __shared__ int hist[512];
    __shared__ int tsum[256];
    const int tid = threadIdx.x;
    const int b = blockIdx.x;
    int slot0 = bucket_slot0(b);
    int nslots = (b < NGB) ? min(64, N_GENE - slot0) : min(512, N_SEG - slot0);
    const int rbase = b * CAP;
    const int E = min(bcur[b], CAP);
    const unsigned* rec = &records[(size_t)b * CAP];

    hist[tid] = 0; hist[tid + 256] = 0;
    __syncthreads();
    for (int i = tid; i < E; i += 256)
        atomicAdd(&hist[rec[i] >> 18], 1);
    __syncthreads();

    int h0 = hist[2 * tid], h1 = hist[2 * tid + 1];
    int ts = h0 + h1;
    tsum[tid] = ts;
    __syncthreads();
    for (int off = 1; off < 256; off <<= 1) {
        int t = (tid >= off) ? tsum[tid - off] : 0;
        __syncthreads();
        tsum[tid] += t;
        __syncthreads();
    }
    int ex = tsum[tid] - ts;
    __syncthreads();
    hist[2 * tid]     = ex;              // becomes the placement cursor
    hist[2 * tid + 1] = ex + h0;
    if (2 * tid < nslots) {
        istart[slot0 + 2 * tid] = rbase + ex;
        iend[slot0 + 2 * tid]   = rbase + ex + h0;
    }
    if (2 * tid + 1 < nslots) {
        istart[slot0 + 2 * tid + 1] = rbase + ex + h0;
        iend[slot0 + 2 * tid + 1]   = rbase + ex + h0 + h1;
    }
    __syncthreads();

    for (int i = tid; i < E; i += 256) {
        unsigned r = rec[i];
        int p = atomicAdd(&hist[r >> 18], 1);
        esrc[rbase + p] = (int)(r & 0x3FFFFu);
    }
}

// ---------------- gather-mean over a bf16 table -----------------------------

__device__ inline void acc_u(float* a, uint4 v) {
    a[0] += __uint_as_float(v.x << 16); a[1] += __uint_as_float(v.x & 0xffff0000u);
    a[2] += __uint_as_float(v.y << 16); a[3] += __uint_as_float(v.y & 0xffff0000u);
    a[4] += __uint_as_float(v.z << 16); a[5] += __uint_as_float(v.z & 0xffff0000u);
    a[6] += __uint_as_float(v.w << 16); a[7] += __uint_as_float(v.w & 0xffff0000u);
}

// Gene-side gather (r6/r8-measured config): 32 lanes/node (16-lane col group
// x 2 edge-list halves), 8-deep unroll; f32 accumulate, bf16 packed output.

__global__ __launch_bounds__(256) void gather_mean_bf16_split_kernel(
        const unsigned short* __restrict__ table,
        const int* __restrict__ istart, const int* __restrict__ iend,
        const int* __restrict__ esrc,
        unsigned short* __restrict__ outb, int n) {
    int lane = threadIdx.x & 15;             // col group
    int half = (threadIdx.x >> 4) & 1;       // edge-list half
    int node = blockIdx.x * 8 + (threadIdx.x >> 5);
    if (node >= n) return;
    int s = istart[node], e = iend[node];
    int deg = e - s;
    int mid = s + ((deg + 1) >> 1);
    int j0 = half ? mid : s;
    int j1 = half ? e   : mid;
    int c = lane << 3;                       // 8 cols per lane
    float acc[8] = {};
    int j = j0;
    for (; j + 8 <= j1; j += 8) {
        int i0 = esrc[j],     i1 = esrc[j + 1], i2 = esrc[j + 2], i3 = esrc[j + 3];
        int i4 = esrc[j + 4], i5 = esrc[j + 5], i6 = esrc[j + 6], i7 = esrc[j + 7];
        uint4 v0 = *(const uint4*)&table[(size_t)i0 * 128 + c];
        uint4 v1 = *(const uint4*)&table[(size_t)i1 * 128 + c];
        uint4 v2 = *(const uint4*)&table[(size_t)i2 * 128 + c];
        uint4 v3 = *(const uint4*)&table[(size_t)i3 * 128 + c];
        uint4 v4 = *(const uint4*)&table[(size_t)i4 * 128 + c];
        uint4 v5 = *(const uint4*)&table[(size_t)i5 * 128 + c];
        uint4 v6 = *(const uint4*)&table[(size_t)i6 * 128 + c];
        uint4 v7 = *(const uint4*)&table[(size_t)i7 * 128 + c];
        acc_u(acc, v0); acc_u(acc, v1); acc_u(acc, v2); acc_u(acc, v3);
        acc_u(acc, v4); acc_u(acc, v5); acc_u(acc, v6); acc_u(acc, v7);
    }
    for (; j + 4 <= j1; j += 4) {
        uint4 v0 = *(const uint4*)&table[(size_t)esrc[j]     * 128 + c];
        uint4 v1 = *(const uint4*)&table[(size_t)esrc[j + 1] * 128 + c];
        uint4 v2 = *(const uint4*)&table[(size_t)esrc[j + 2] * 128 + c];
        uint4 v3 = *(const uint4*)&table[(size_t)esrc[j + 3] * 128 + c];
        acc_u(acc, v0); acc_u(acc, v1); acc_u(acc, v2); acc_u(acc, v3);
    }
    for (; j < j1; ++j) {
        uint4 v = *(const uint4*)&table[(size_t)esrc[j] * 128 + c];
        acc_u(acc, v);
    }
    #pragma unroll
    for (int q = 0; q < 8; ++q) acc[q] += __shfl_xor(acc[q], 16);
    if (half == 0) {
        float inv = (deg > 0) ? 1.f / (float)deg : 0.f;
        #pragma unroll
        for (int q = 0; q < 8; ++q) acc[q] *= inv;
        uint4 w;
        w.x = bf16rne(acc[0]) | (bf16rne(acc[1]) << 16);
        w.y = bf16rne(acc[2]) | (bf16rne(acc[3]) << 16);
        w.z = bf16rne(acc[4]) | (bf16rne(acc[5]) << 16);
        w.w = bf16rne(acc[6]) | (bf16rne(acc[7]) << 16);
        *(uint4*)&outb[(size_t)node * 128 + c] = w;
    }
}

// Chem-side gather (r6/r8-measured config): 16 lanes/node, deg ~5, f32 NT out.

template<bool NT>
__global__ __launch_bounds__(256) void gather_mean_bf16_kernel(
        const unsigned short* __restrict__ table,
        const int* __restrict__ istart, const int* __restrict__ iend,
        const int* __restrict__ esrc,
        float* __restrict__ out, int n) {
    int lane = threadIdx.x & 15;
    int node = blockIdx.x * 16 + (threadIdx.x >> 4);
    if (node >= n) return;
    int s = istart[node], e = iend[node];
    int c = lane << 3;                       // 8 cols per lane
    float acc[8] = {};
    int j = s;
    for (; j + 4 <= e; j += 4) {
        uint4 v0 = *(const uint4*)&table[(size_t)esrc[j]     * 128 + c];
        uint4 v1 = *(const uint4*)&table[(size_t)esrc[j + 1] * 128 + c];
        uint4 v2 = *(const uint4*)&table[(size_t)esrc[j + 2] * 128 + c];
        uint4 v3 = *(const uint4*)&table[(size_t)esrc[j + 3] * 128 + c];
        acc_u(acc, v0); acc_u(acc, v1); acc_u(acc, v2); acc_u(acc, v3);
    }
    for (; j < e; ++j) {
        uint4 v = *(const uint4*)&table[(size_t)esrc[j] * 128 + c];
        acc_u(acc, v);
    }
    int deg = e - s;
    float inv = (deg > 0) ? 1.f / (float)deg : 0.f;
    #pragma unroll
    for (int q = 0; q < 8; ++q) acc[q] *= inv;
    float* dst = &out[(size_t)node * 128 + c];
    if (NT) {
        nfloat4 a = { acc[0], acc[1], acc[2], acc[3] };
        nfloat4 b = { acc[4], acc[5], acc[6], acc[7] };
        __builtin_nontemporal_store(a, (nfloat4*)dst);
        __builtin_nontemporal_store(b, (nfloat4*)(dst + 4));
    } else {
        *(float4*)dst       = make_float4(acc[0], acc[1], acc[2], acc[3]);
        *(float4*)(dst + 4) = make_float4(acc[4], acc[5], acc[6], acc[7]);
    }
}

// ---------------- gather-mean over an f32 table (ws-fallback path) ----------

__global__ __launch_bounds__(256) void gather_mean_f32_kernel(
        const float* __restrict__ table,
        const int* __restrict__ istart, const int* __restrict__ iend,
        const int* __restrict__ esrc,
        float* __restrict__ out, int n) {
    int lane = threadIdx.x & 31;
    int node = blockIdx.x * 8 + (threadIdx.x >> 5);
    if (node >= n) return;
    int s = istart[node], e = iend[node];
    int c = lane << 2;
    float4 acc = make_float4(0.f, 0.f, 0.f, 0.f);
    int j = s;
    for (; j + 4 <= e; j += 4) {
        int s0 = esrc[j], s1 = esrc[j + 1], s2 = esrc[j + 2], s3 = esrc[j + 3];
        float4 v0 = *(const float4*)&table[(size_t)s0 * 128 + c];
        float4 v1 = *(const float4*)&table[(size_t)s1 * 128 + c];
        float4 v2 = *(const float4*)&table[(size_t)s2 * 128 + c];
        float4 v3 = *(const float4*)&table[(size_t)s3 * 128 + c];
        acc.x += (v0.x + v1.x) + (v2.x + v3.x);
        acc.y += (v0.y + v1.y) + (v2.y + v3.y);
        acc.z += (v0.z + v1.z) + (v2.z + v3.z);
        acc.w += (v0.w + v1.w) + (v2.w + v3.w);
    }
    for (; j < e; ++j) {
        float4 v = *(const float4*)&table[(size_t)esrc[j] * 128 + c];
        acc.x += v.x; acc.y += v.y; acc.z += v.z; acc.w += v.w;
    }
    int deg = e - s;
    float inv = (deg > 0) ? 1.f / (float)deg : 0.f;
    acc.x *= inv; acc.y *= inv; acc.z *= inv; acc.w *= inv;
    *(float4*)&out[(size_t)node * 128 + c] = acc;
}

// ---------------- fused bf16 MFMA GEMM: Wh2 = (leaky/mask(A@W1+b1)) @ W2 + b2
// One 64-row tile per block. Phase 1 keeps the 256-wide hidden tile in LDS
// as bf16 (same rounding point as the old h_geneb store -> identical output),
// phase 2 consumes it directly. Kills the 20 MB h_gene HBM round-trip + one
// dispatch. LDS 68 KB -> 2 blk/CU. C/D layout: col=lane&15, row=(lane>>4)*4+r.

__global__ __launch_bounds__(256) void gemm_fused_kernel(
        const unsigned short* __restrict__ A,    // agg1b [M][128] bf16
        const float* __restrict__ W1,            // [128][256] f32
        const float* __restrict__ b1,            // [256]
        const float* __restrict__ W2,            // [256][128] f32
        const float* __restrict__ b2,            // [128]
        const int* __restrict__ istart, const int* __restrict__ iend,
        unsigned short* __restrict__ C,          // [M][128] bf16
        int M) {
    constexpr int LDK = 136;                     // 128 + 8 pad (2-way banks, free)
    constexpr int LDH = 264;                     // 256 + 8 pad
    __shared__ unsigned short SAB[2 * 64 * LDK]; // 34 KB: As|Ws (ph1) = Ws2 (ph2)
    __shared__ unsigned short Ht[64 * LDH];      // 33 KB hidden tile (bf16)
    unsigned short* As = SAB;
    unsigned short* Ws = SAB + 64 * LDK;
    const int tid  = threadIdx.x;
    const int lane = tid & 63;
    const int w    = tid >> 6;                   // wave: rows w*16..+15
    const int m0   = blockIdx.x * 64;
    const int l15  = lane & 15;
    const int lhi  = lane >> 4;                  // 0..3

    // ---- phase 1: Ht = leaky(mask(A @ W1 + b1)) ----
    #pragma unroll
    for (int it = 0; it < 4; ++it) {
        int idx = it * 256 + tid;
        int row = idx >> 4;
        int c8  = (idx & 15) << 3;
        uint4 v = make_uint4(0u, 0u, 0u, 0u);
        if (m0 + row < M)
            v = *(const uint4*)&A[(size_t)(m0 + row) * IN_D + c8];
        *(uint4*)&As[row * LDK + c8] = v;
    }
    for (int n0c = 0; n0c < HID_D; n0c += 64) {
        __syncthreads();                         // prev MFMA done -> Ws free
        #pragma unroll
        for (int it = 0; it < 32; ++it) {
            int i = it * 256 + tid;
            int k = i >> 6;                      // 0..127
            int n = i & 63;
            Ws[n * LDK + k] = (unsigned short)bf16rne(W1[(size_t)k * HID_D + n0c + n]);
        }
        __syncthreads();
        f32x4 acc[4] = {};
        #pragma unroll
        for (int kk = 0; kk < 128; kk += 32) {
            bf16x8 a = *(const bf16x8*)&As[(w * 16 + l15) * LDK + kk + lhi * 8];
            #pragma unroll
            for (int nt = 0; nt < 4; ++nt) {
                bf16x8 b = *(const bf16x8*)&Ws[(nt * 16 + l15) * LDK + kk + lhi * 8];
                acc[nt] = __builtin_amdgcn_mfma_f32_16x16x32_bf16(a, b, acc[nt], 0, 0, 0);
            }
        }
        #pragma unroll
        for (int nt = 0; nt < 4; ++nt) {
            int col = n0c + nt * 16 + l15;
            float bz = b1[col];
            #pragma unroll
            for (int r = 0; r < 4; ++r) {
                int row = w * 16 + lhi * 4 + r;
                if (m0 + row < M) {
                    float v = acc[nt][r] + bz;
                    int deg = iend[m0 + row] - istart[m0 + row];
                    v = (deg == 0) ? 0.f : (v > 0.f ? v : 0.01f * v);
                    Ht[row * LDH + col] = (unsigned short)bf16rne(v);
                }
            }
        }
    }
    __syncthreads();                             // Ht complete; SAB free

    // ---- phase 2: C = Ht @ W2 + b2 ----
    f32x4 acc2[8] = {};
    for (int kt = 0; kt < HID_D; kt += 128) {
        #pragma unroll
        for (int it = 0; it < 64; ++it) {
            int i = it * 256 + tid;
            int k = i >> 7;                      // 0..127
            int n = i & 127;
            SAB[n * LDK + k] = (unsigned short)bf16rne(W2[(size_t)(kt + k) * OUT_D + n]);
        }
        __syncthreads();
        #pragma unroll
        for (int kk = 0; kk < 128; kk += 32) {
            bf16x8 a = *(const bf16x8*)&Ht[(w * 16 + l15) * LDH + kt + kk + lhi * 8];
            #pragma unroll
            for (int nt = 0; nt < 8; ++nt) {
                bf16x8 b = *(const bf16x8*)&SAB[(nt * 16 + l15) * LDK + kk + lhi * 8];
                acc2[nt] = __builtin_amdgcn_mfma_f32_16x16x32_bf16(a, b, acc2[nt], 0, 0, 0);
            }
        }
        __syncthreads();                         // before restaging SAB
    }
    #pragma unroll
    for (int nt = 0; nt < 8; ++nt) {
        int col = nt * 16 + l15;
        float bz = b2[col];
        #pragma unroll
        for (int r = 0; r < 4; ++r) {
            int row = m0 + w * 16 + lhi * 4 + r;
            if (row < M) {
                float v = acc2[nt][r] + bz;
                C[(size_t)row * OUT_D + col] = (unsigned short)bf16rne(v);
            }
        }
    }
}

// ---------------- f32 VALU GEMM (ws-fallback path only) ---------------------

template<int K, int N, bool MASK_LEAKY, bool BF16_OUT>
__global__ __launch_bounds__(256) void gemm_kernel(const float* __restrict__ A,
                                                   const float* __restrict__ W,
                                                   const float* __restrict__ bias,
                                                   const int* __restrict__ istart,
                                                   const int* __restrict__ iend,
                                                   void* __restrict__ Cout, int M) {
    __shared__ float As[64 * 68];
    __shared__ float Ws[64 * 64];
    const int tid = threadIdx.x;
    const int tx = tid & 15, ty = tid >> 4;
    const int m0 = blockIdx.x * 64;
    const int n0 = blockIdx.y * 64;
    const int r0 = ty << 2, c0 = tx << 2;
    float acc[4][4] = {};

    for (int kt = 0; kt < K; kt += 64) {
        #pragma unroll
        for (int q = 0; q < 4; ++q) {
            int idx = tid + q * 256;
            int row = idx >> 4;
            int c4  = (idx & 15) << 2;
            float4 v = make_float4(0.f, 0.f, 0.f, 0.f);
            if (m0 + row < M)
                v = *(const float4*)&A[(size_t)(m0 + row) * K + kt + c4];
            *(float4*)&As[row * 68 + c4] = v;
        }
        #pragma unroll
        for (int q = 0; q < 4; ++q) {
            int idx = tid + q * 256;
            int k   = idx >> 4;
            int c4  = (idx & 15) << 2;
            *(float4*)&Ws[(k << 6) + c4] =
                *(const float4*)&W[(size_t)(kt + k) * N + n0 + c4];
        }
        __syncthreads();

        #pragma unroll 4
        for (int k = 0; k < 64; k += 4) {
            float a[4][4];
            #pragma unroll
            for (int r = 0; r < 4; ++r) {
                float4 v = *(const float4*)&As[(r0 + r) * 68 + k];
                a[r][0] = v.x; a[r][1] = v.y; a[r][2] = v.z; a[r][3] = v.w;
            }
            #pragma unroll
            for (int kk = 0; kk < 4; ++kk) {
                float4 w = *(const float4*)&Ws[((k + kk) << 6) + c0];
                #pragma unroll
                for (int r = 0; r < 4; ++r) {
                    acc[r][0] = fmaf(a[r][kk], w.x, acc[r][0]);
                    acc[r][1] = fmaf(a[r][kk], w.y, acc[r][1]);
                    acc[r][2] = fmaf(a[r][kk], w.z, acc[r][2]);
                    acc[r][3] = fmaf(a[r][kk], w.w, acc[r][3]);
                }
            }
        }
        __syncthreads();
    }

    float4 b = *(const float4*)&bias[n0 + c0];
    #pragma unroll
    for (int r = 0; r < 4; ++r) {
        int row = m0 + r0 + r;
        if (row < M) {
            float4 v;
            v.x = acc[r][0] + b.x; v.y = acc[r][1] + b.y;
            v.z = acc[r][2] + b.z; v.w = acc[r][3] + b.w;
            if (MASK_LEAKY) {
                int deg = iend[row] - istart[row];
                if (deg == 0) {
                    v = make_float4(0.f, 0.f, 0.f, 0.f);
                } else {
                    v.x = v.x > 0.f ? v.x : 0.01f * v.x;
                    v.y = v.y > 0.f ? v.y : 0.01f * v.y;
                    v.z = v.z > 0.f ? v.z : 0.01f * v.z;
                    v.w = v.w > 0.f ? v.w : 0.01f * v.w;
                }
            }
            if (BF16_OUT) {
                uint2 w;
                w.x = bf16rne(v.x) | (bf16rne(v.y) << 16);
                w.y = bf16rne(v.z) | (bf16rne(v.w) << 16);
                *(uint2*)&((unsigned short*)Cout)[(size_t)row * N + n0 + c0] = w;
            } else {
                *(float4*)&((float*)Cout)[(size_t)row * N + n0 + c0] = v;
            }
        }
    }
}

// ---------------- launch ----------------

extern "C" void kernel_launch(void* const* d_in, const int* in_sizes, int n_in,
                              void* d_out, int out_size, void* d_ws, size_t ws_size,
                              hipStream_t stream) {
    const int*   src_cg     = (const int*)d_in[0];
    const int*   dst_cg     = (const int*)d_in[1];
    const int*   src_gc     = (const int*)d_in[2];
    const int*   dst_gc     = (const int*)d_in[3];
    const float* embed_chem = (const float*)d_in[4];
    const float* W1_cg = (const float*)d_in[6];
    const float* b1_cg = (const float*)d_in[7];
    const float* W2_gc = (const float*)d_in[12];
    const float* b2_gc = (const float*)d_in[13];
    float* out = (float*)d_out;

    // workspace layout (int words)
    int* ws_i = (int*)d_ws;
    size_t off = 0;
    int* bcur   = ws_i + off; off += NB;         // zeroed each launch
    int* istart = ws_i + off; off += N_SEG;
    int* iend   = ws_i + off; off += N_SEG;
    off = (off + 3) & ~(size_t)3;
    int* esrc   = ws_i + off; off += (size_t)NB * CAP;   // CAP-strided (23 MB)
    // records (NB*CAP ints) is dead before agg1/h_gene are written -> overlay
    size_t union_off = off;
    unsigned* records = (unsigned*)(ws_i + union_off);
    unsigned short* agg1b = (unsigned short*)(ws_i + union_off);
    float* agg1f   = (float*)(ws_i + union_off);
    float* h_genef = agg1f + (size_t)N_GENE * IN_D;
    size_t union_sz = (size_t)NB * CAP;                  // 5.77M ints
    if (union_sz < (size_t)N_GENE * (IN_D + HID_D)) union_sz = (size_t)N_GENE * (IN_D + HID_D);
    off = union_off + union_sz;
    unsigned short* Wh2b = (unsigned short*)(ws_i + off); off += (size_t)N_GENE * OUT_D / 2;
    unsigned short* embedb = (unsigned short*)(ws_i + off);
    size_t off_full = off + (size_t)N_CHEM * IN_D / 2;
    const bool bf16_embed = ws_size >= off_full * sizeof(int);   // launch-constant

    (void)hipMemsetAsync(bcur, 0, NB * sizeof(int), stream);

    // ---- CSR build + (overlapped) embed conversion; no scan dispatch needed
    const int nconv = bf16_embed ? (N_CHEM * IN_D / 4 + 1023) / 1024 : 0;  // 6250
    place_convert_kernel<<<NBA + nconv, 256, 0, stream>>>(
        src_cg, dst_cg, src_gc, dst_gc, bcur, records, embed_chem, embedb);
    bin_b_kernel<<<NB, 256, 0, stream>>>(records, bcur, istart, iend, esrc);

    if (bf16_embed) {
        // layer 1 aggregate (mean is linear; project after), bf16 output
        gather_mean_bf16_split_kernel<<<(N_GENE + 7) / 8, 256, 0, stream>>>(
            embedb, istart, iend, esrc, agg1b, N_GENE);
        // fused: Wh2 = (leaky/mask(agg1 @ W1 + b1)) @ W2 + b2
        gemm_fused_kernel<<<(N_GENE + 63) / 64, 256, 0, stream>>>(
            agg1b, W1_cg, b1_cg, W2_gc, b2_gc, istart, iend, Wh2b, N_GENE);
    } else {
        gather_mean_f32_kernel<<<(N_GENE + 7) / 8, 256, 0, stream>>>(
            embed_chem, istart, iend, esrc, agg1f, N_GENE);
        {
            dim3 g((N_GENE + 63) / 64, HID_D / 64), blk(256);
            gemm_kernel<IN_D, HID_D, true, false><<<g, blk, 0, stream>>>(
                agg1f, W1_cg, b1_cg, istart, iend, h_genef, N_GENE);
        }
        {
            dim3 g((N_GENE + 63) / 64, OUT_D / 64), blk(256);
            gemm_kernel<HID_D, OUT_D, false, true><<<g, blk, 0, stream>>>(
                h_genef, W2_gc, b2_gc, istart, iend, Wh2b, N_GENE);
        }
    }

    // out = seg_mean(Wh2[src_gc], dst_gc, N_CHEM)  (chem segments start at N_GENE)
    gather_mean_bf16_kernel<true><<<(N_CHEM + 15) / 16, 256, 0, stream>>>(
        Wh2b, istart + N_GENE, iend + N_GENE, esrc, out, N_CHEM);
}

// Round 10
// 331.253 us; speedup vs baseline: 1.1500x; 1.1500x over previous
//
#include <hip/hip_runtime.h>
#include <stdint.h>
#include <stddef.h>

#define N_CHEM 200000
#define N_GENE 20000
#define N_EDGES 1000000
#define IN_D 128
#define HID_D 256
#define OUT_D 128
#define N_SEG (N_GENE + N_CHEM)          // 220000 concatenated segments

// ---- bucket decomposition of the segment space -----------------------------
#define NGB 313
#define NCB 391
#define NB  (NGB + NCB)                  // 704
#define EPB 4096                         // r4/r8-measured best
#define NBA ((2 * N_EDGES + EPB - 1) / EPB)   // 489 place blocks
#define NCONV 6250                       // embed-convert blocks (bf16 path)
#define NWT 16                           // weight transpose blocks (8 W1 + 8 W2)
#define CAP 8192                         // per-bucket capacity (exp<=3500)
#define DROPPED 0x80000000               // overflow sentinel (never hit)

typedef float nfloat4 __attribute__((ext_vector_type(4)));   // native vec for NT store
typedef __attribute__((ext_vector_type(8))) short bf16x8;    // 8 bf16 = 4 VGPRs
typedef __attribute__((ext_vector_type(4))) float f32x4;

__device__ inline unsigned bf16rne(float x) {
    unsigned u = __float_as_uint(x);
    return (u + 0x7FFFu + ((u >> 16) & 1u)) >> 16;
}

__device__ inline int bucket_of(int slot) {
    return (slot < N_GENE) ? (slot >> 6) : (NGB + ((slot - N_GENE) >> 9));
}
__device__ inline int bucket_slot0(int b) {
    return (b < NGB) ? (b << 6) : (N_GENE + ((b - NGB) << 9));
}

// ---------------- CSR build ------------------------------------------------
// Pass A (fused): [0,NBA) scatter packed (local_slot<<18|src) records into
// fixed-capacity bucket regions (LDS-ordered -> coalesced run writes);
// [NBA,NBA+NCONV) f32->bf16 embed conversion; [NBA+NCONV,+NWT) weight
// transpose+convert (W1t[n][k], W2t[n][k] bf16) so GEMM blocks can stage W
// with vectorized loads (r9 lesson: per-block scalar cvt staging = 2.7M LDS
// bank conflicts). Measured notes: ~64us at 4 AND 5 blk/CU (throughput-bound,
// not occupancy); r7: column-slicing = 2x FETCH (128B granule, blockIdx !~
// XCD); r5: per-block __threadfence = 100us.

__global__ __launch_bounds__(256) void place_convert_kernel(
        const int* __restrict__ src_cg, const int* __restrict__ dst_cg,
        const int* __restrict__ src_gc, const int* __restrict__ dst_gc,
        int* __restrict__ bcur, unsigned* __restrict__ records,
        const float* __restrict__ conv_in, unsigned short* __restrict__ conv_out,
        const float* __restrict__ W1, const float* __restrict__ W2,
        unsigned short* __restrict__ W1t, unsigned short* __restrict__ W2t) {
    __shared__ unsigned stage_rec[EPB];        // 16 KB packed records (reused as tile)
    __shared__ unsigned short stage_bkt[EPB];  // 8 KB bucket ids
    __shared__ int hist[NB];
    __shared__ int cursor[NB];
    __shared__ int tsum[256];
    const int tid = threadIdx.x;
    const int bid = blockIdx.x;

    if (bid >= NBA + NCONV) {
        // ---- weight transpose path: one 64x64 tile per block ----
        unsigned short* tile = (unsigned short*)stage_rec;   // [64][65]
        int wb = bid - NBA - NCONV;
        const float* Wsrc; unsigned short* Wdst; int K, N, kt0, n0;
        if (wb < 8) { Wsrc = W1; Wdst = W1t; K = 128; N = 256;
                      kt0 = (wb >> 2) * 64; n0 = (wb & 3) * 64; }
        else        { wb -= 8; Wsrc = W2; Wdst = W2t; K = 256; N = 128;
                      kt0 = (wb >> 1) * 64; n0 = (wb & 1) * 64; }
        #pragma unroll
        for (int it = 0; it < 16; ++it) {
            int idx = it * 256 + tid;
            int r = idx >> 6, c = idx & 63;
            tile[c * 65 + r] = (unsigned short)bf16rne(Wsrc[(size_t)(kt0 + r) * N + n0 + c]);
        }
        __syncthreads();
        #pragma unroll
        for (int it = 0; it < 16; ++it) {
            int idx = it * 256 + tid;
            int r = idx >> 6, c = idx & 63;
            Wdst[(size_t)(n0 + r) * K + kt0 + c] = tile[r * 65 + c];
        }
        return;
    }
    if (bid >= NBA) {
        // ---- embed conversion path: 1024 float4 per block ----
        int cb = bid - NBA;
        #pragma unroll
        for (int q = 0; q < 4; ++q) {
            int i = cb * 1024 + q * 256 + tid;
            if (i < N_CHEM * IN_D / 4) {
                float4 v = *(const float4*)&conv_in[(size_t)i * 4];
                uint2 w;
                w.x = bf16rne(v.x) | (bf16rne(v.y) << 16);
                w.y = bf16rne(v.z) | (bf16rne(v.w) << 16);
                *(uint2*)&conv_out[(size_t)i * 4] = w;
            }
        }
        return;
    }
    // ---- place path ----
    const int e0 = bid * EPB;
    const int cnt_blk = min(EPB, 2 * N_EDGES - e0);

    for (int i = tid; i < NB; i += 256) hist[i] = 0;
    __syncthreads();

    int slotR[EPB / 256], srcR[EPB / 256];
    #pragma unroll
    for (int q = 0; q < EPB / 256; ++q) {
        int e = e0 + q * 256 + tid;
        int slot = -1, s = 0;
        if (e < N_EDGES)            { slot = dst_cg[e];                    s = src_cg[e]; }
        else if (e < 2 * N_EDGES)   { slot = N_GENE + dst_gc[e - N_EDGES]; s = src_gc[e - N_EDGES]; }
        slotR[q] = slot; srcR[q] = s;
        if (slot >= 0) atomicAdd(&hist[bucket_of(slot)], 1);
    }
    __syncthreads();

    const int b3 = tid * 3;
    int h0 = (b3     < NB) ? hist[b3]     : 0;
    int h1 = (b3 + 1 < NB) ? hist[b3 + 1] : 0;
    int h2 = (b3 + 2 < NB) ? hist[b3 + 2] : 0;
    int ts = h0 + h1 + h2;
    tsum[tid] = ts;
    __syncthreads();
    for (int off = 1; off < 256; off <<= 1) {
        int t = (tid >= off) ? tsum[tid - off] : 0;
        __syncthreads();
        tsum[tid] += t;
        __syncthreads();
    }
    int base = tsum[tid] - ts;
    if (b3     < NB) cursor[b3]     = base;
    if (b3 + 1 < NB) cursor[b3 + 1] = base + h0;
    if (b3 + 2 < NB) cursor[b3 + 2] = base + h0 + h1;
    __syncthreads();

    #pragma unroll
    for (int q = 0; q < EPB / 256; ++q) {
        int slot = slotR[q];
        if (slot >= 0) {
            int b = bucket_of(slot);
            int p = atomicAdd(&cursor[b], 1);
            stage_rec[p] = ((unsigned)(slot - bucket_slot0(b)) << 18) | (unsigned)srcR[q];
            stage_bkt[p] = (unsigned short)b;
        }
    }
    __syncthreads();

    for (int i = tid; i < NB; i += 256) {
        int n = hist[i];
        if (n) {
            int got = atomicAdd(&bcur[i], n);
            int excl_i = cursor[i] - n;          // cursor is now excl+n
            hist[i] = (got + n <= CAP) ? (i * CAP + got - excl_i) : (int)DROPPED;
        }
    }
    __syncthreads();

    for (int i = tid; i < cnt_blk; i += 256) {
        int d = hist[stage_bkt[i]];
        if (d != (int)DROPPED) records[i + d] = stage_rec[i];
    }
}

// Pass B: one block per bucket -> local histogram+scan -> istart/iend + esrc.
// esrc lives in the CAP-strided bucket regions; no global scan dispatch.

__global__ __launch_bounds__(256) void bin_b_kernel(
        const unsigned* __restrict__ records, const int* __restrict__ bcur,
        int* __restrict__ istart, int* __restrict__ iend, int* __restrict__ esrc) {
    __shared__ int hist[512];
    __shared__ int tsum[256];
    const int tid = threadIdx.x;
    const int b = blockIdx.x;
    int slot0 = bucket_slot0(b);
    int nslots = (b < NGB) ? min(64, N_GENE - slot0) : min(512, N_SEG - slot0);
    const int rbase = b * CAP;
    const int E = min(bcur[b], CAP);
    const unsigned* rec = &records[(size_t)b * CAP];

    hist[tid] = 0; hist[tid + 256] = 0;
    __syncthreads();
    for (int i = tid; i < E; i += 256)
        atomicAdd(&hist[rec[i] >> 18], 1);
    __syncthreads();

    int h0 = hist[2 * tid], h1 = hist[2 * tid + 1];
    int ts = h0 + h1;
    tsum[tid] = ts;
    __syncthreads();
    for (int off = 1; off < 256; off <<= 1) {
        int t = (tid >= off) ? tsum[tid - off] : 0;
        __syncthreads();
        tsum[tid] += t;
        __syncthreads();
    }
    int ex = tsum[tid] - ts;
    __syncthreads();
    hist[2 * tid]     = ex;              // becomes the placement cursor
    hist[2 * tid + 1] = ex + h0;
    if (2 * tid < nslots) {
        istart[slot0 + 2 * tid] = rbase + ex;
        iend[slot0 + 2 * tid]   = rbase + ex + h0;
    }
    if (2 * tid + 1 < nslots) {
        istart[slot0 + 2 * tid + 1] = rbase + ex + h0;
        iend[slot0 + 2 * tid + 1]   = rbase + ex + h0 + h1;
    }
    __syncthreads();

    for (int i = tid; i < E; i += 256) {
        unsigned r = rec[i];
        int p = atomicAdd(&hist[r >> 18], 1);
        esrc[rbase + p] = (int)(r & 0x3FFFFu);
    }
}

// ---------------- gather-mean over a bf16 table -----------------------------

__device__ inline void acc_u(float* a, uint4 v) {
    a[0] += __uint_as_float(v.x << 16); a[1] += __uint_as_float(v.x & 0xffff0000u);
    a[2] += __uint_as_float(v.y << 16); a[3] += __uint_as_float(v.y & 0xffff0000u);
    a[4] += __uint_as_float(v.z << 16); a[5] += __uint_as_float(v.z & 0xffff0000u);
    a[6] += __uint_as_float(v.w << 16); a[7] += __uint_as_float(v.w & 0xffff0000u);
}

// Gene-side gather (r6/r8-measured): 32 lanes/node (16-lane col group x 2
// edge-list halves), 8-deep unroll; f32 accumulate, bf16 packed output.

__global__ __launch_bounds__(256) void gather_mean_bf16_split_kernel(
        const unsigned short* __restrict__ table,
        const int* __restrict__ istart, const int* __restrict__ iend,
        const int* __restrict__ esrc,
        unsigned short* __restrict__ outb, int n) {
    int lane = threadIdx.x & 15;             // col group
    int half = (threadIdx.x >> 4) & 1;       // edge-list half
    int node = blockIdx.x * 8 + (threadIdx.x >> 5);
    if (node >= n) return;
    int s = istart[node], e = iend[node];
    int deg = e - s;
    int mid = s + ((deg + 1) >> 1);
    int j0 = half ? mid : s;
    int j1 = half ? e   : mid;
    int c = lane << 3;                       // 8 cols per lane
    float acc[8] = {};
    int j = j0;
    for (; j + 8 <= j1; j += 8) {
        int i0 = esrc[j],     i1 = esrc[j + 1], i2 = esrc[j + 2], i3 = esrc[j + 3];
        int i4 = esrc[j + 4], i5 = esrc[j + 5], i6 = esrc[j + 6], i7 = esrc[j + 7];
        uint4 v0 = *(const uint4*)&table[(size_t)i0 * 128 + c];
        uint4 v1 = *(const uint4*)&table[(size_t)i1 * 128 + c];
        uint4 v2 = *(const uint4*)&table[(size_t)i2 * 128 + c];
        uint4 v3 = *(const uint4*)&table[(size_t)i3 * 128 + c];
        uint4 v4 = *(const uint4*)&table[(size_t)i4 * 128 + c];
        uint4 v5 = *(const uint4*)&table[(size_t)i5 * 128 + c];
        uint4 v6 = *(const uint4*)&table[(size_t)i6 * 128 + c];
        uint4 v7 = *(const uint4*)&table[(size_t)i7 * 128 + c];
        acc_u(acc, v0); acc_u(acc, v1); acc_u(acc, v2); acc_u(acc, v3);
        acc_u(acc, v4); acc_u(acc, v5); acc_u(acc, v6); acc_u(acc, v7);
    }
    for (; j + 4 <= j1; j += 4) {
        uint4 v0 = *(const uint4*)&table[(size_t)esrc[j]     * 128 + c];
        uint4 v1 = *(const uint4*)&table[(size_t)esrc[j + 1] * 128 + c];
        uint4 v2 = *(const uint4*)&table[(size_t)esrc[j + 2] * 128 + c];
        uint4 v3 = *(const uint4*)&table[(size_t)esrc[j + 3] * 128 + c];
        acc_u(acc, v0); acc_u(acc, v1); acc_u(acc, v2); acc_u(acc, v3);
    }
    for (; j < j1; ++j) {
        uint4 v = *(const uint4*)&table[(size_t)esrc[j] * 128 + c];
        acc_u(acc, v);
    }
    #pragma unroll
    for (int q = 0; q < 8; ++q) acc[q] += __shfl_xor(acc[q], 16);
    if (half == 0) {
        float inv = (deg > 0) ? 1.f / (float)deg : 0.f;
        #pragma unroll
        for (int q = 0; q < 8; ++q) acc[q] *= inv;
        uint4 w;
        w.x = bf16rne(acc[0]) | (bf16rne(acc[1]) << 16);
        w.y = bf16rne(acc[2]) | (bf16rne(acc[3]) << 16);
        w.z = bf16rne(acc[4]) | (bf16rne(acc[5]) << 16);
        w.w = bf16rne(acc[6]) | (bf16rne(acc[7]) << 16);
        *(uint4*)&outb[(size_t)node * 128 + c] = w;
    }
}

// Chem-side gather (r6/r8-measured): 16 lanes/node, deg ~5, f32 NT output.

template<bool NT>
__global__ __launch_bounds__(256) void gather_mean_bf16_kernel(
        const unsigned short* __restrict__ table,
        const int* __restrict__ istart, const int* __restrict__ iend,
        const int* __restrict__ esrc,
        float* __restrict__ out, int n) {
    int lane = threadIdx.x & 15;
    int node = blockIdx.x * 16 + (threadIdx.x >> 4);
    if (node >= n) return;
    int s = istart[node], e = iend[node];
    int c = lane << 3;                       // 8 cols per lane
    float acc[8] = {};
    int j = s;
    for (; j + 4 <= e; j += 4) {
        uint4 v0 = *(const uint4*)&table[(size_t)esrc[j]     * 128 + c];
        uint4 v1 = *(const uint4*)&table[(size_t)esrc[j + 1] * 128 + c];
        uint4 v2 = *(const uint4*)&table[(size_t)esrc[j + 2] * 128 + c];
        uint4 v3 = *(const uint4*)&table[(size_t)esrc[j + 3] * 128 + c];
        acc_u(acc, v0); acc_u(acc, v1); acc_u(acc, v2); acc_u(acc, v3);
    }
    for (; j < e; ++j) {
        uint4 v = *(const uint4*)&table[(size_t)esrc[j] * 128 + c];
        acc_u(acc, v);
    }
    int deg = e - s;
    float inv = (deg > 0) ? 1.f / (float)deg : 0.f;
    #pragma unroll
    for (int q = 0; q < 8; ++q) acc[q] *= inv;
    float* dst = &out[(size_t)node * 128 + c];
    if (NT) {
        nfloat4 a = { acc[0], acc[1], acc[2], acc[3] };
        nfloat4 b = { acc[4], acc[5], acc[6], acc[7] };
        __builtin_nontemporal_store(a, (nfloat4*)dst);
        __builtin_nontemporal_store(b, (nfloat4*)(dst + 4));
    } else {
        *(float4*)dst       = make_float4(acc[0], acc[1], acc[2], acc[3]);
        *(float4*)(dst + 4) = make_float4(acc[4], acc[5], acc[6], acc[7]);
    }
}

// ---------------- gather-mean over an f32 table (ws-fallback path) ----------

__global__ __launch_bounds__(256) void gather_mean_f32_kernel(
        const float* __restrict__ table,
        const int* __restrict__ istart, const int* __restrict__ iend,
        const int* __restrict__ esrc,
        float* __restrict__ out, int n) {
    int lane = threadIdx.x & 31;
    int node = blockIdx.x * 8 + (threadIdx.x >> 5);
    if (node >= n) return;
    int s = istart[node], e = iend[node];
    int c = lane << 2;
    float4 acc = make_float4(0.f, 0.f, 0.f, 0.f);
    int j = s;
    for (; j + 4 <= e; j += 4) {
        int s0 = esrc[j], s1 = esrc[j + 1], s2 = esrc[j + 2], s3 = esrc[j + 3];
        float4 v0 = *(const float4*)&table[(size_t)s0 * 128 + c];
        float4 v1 = *(const float4*)&table[(size_t)s1 * 128 + c];
        float4 v2 = *(const float4*)&table[(size_t)s2 * 128 + c];
        float4 v3 = *(const float4*)&table[(size_t)s3 * 128 + c];
        acc.x += (v0.x + v1.x) + (v2.x + v3.x);
        acc.y += (v0.y + v1.y) + (v2.y + v3.y);
        acc.z += (v0.z + v1.z) + (v2.z + v3.z);
        acc.w += (v0.w + v1.w) + (v2.w + v3.w);
    }
    for (; j < e; ++j) {
        float4 v = *(const float4*)&table[(size_t)esrc[j] * 128 + c];
        acc.x += v.x; acc.y += v.y; acc.z += v.z; acc.w += v.w;
    }
    int deg = e - s;
    float inv = (deg > 0) ? 1.f / (float)deg : 0.f;
    acc.x *= inv; acc.y *= inv; acc.z *= inv; acc.w *= inv;
    *(float4*)&out[(size_t)node * 128 + c] = acc;
}

// ---------------- bf16 MFMA GEMM: C[M,N](bf16) = A[M,K](bf16) @ Wt^T + bias -
// Wt is PRE-TRANSPOSED bf16 [N][K] (from the place_convert weight blocks), so
// W staging = coalesced uint4 loads + ds_write_b128 (same pattern as A stage)
// instead of r9's 8K scalar cvt+b16 scatters (2.7M bank conflicts).

template<int K, int N, bool MASK_LEAKY>
__global__ __launch_bounds__(256) void gemm_mfma_kernel(
        const unsigned short* __restrict__ A,    // [M][K] bf16
        const unsigned short* __restrict__ Wt,   // [N][K] bf16 (transposed)
        const float* __restrict__ bias,          // [N] f32
        const int* __restrict__ istart, const int* __restrict__ iend,
        unsigned short* __restrict__ C,          // [M][N] bf16
        int M) {
    constexpr int BK  = 128;
    constexpr int LDK = BK + 8;                  // +16B pad
    __shared__ unsigned short As[64 * LDK];      // 17 KB
    __shared__ unsigned short Ws[64 * LDK];      // 17 KB: Ws[n][k]
    const int tid  = threadIdx.x;
    const int lane = tid & 63;
    const int w    = tid >> 6;                   // wave: output rows w*16..+15
    const int m0 = blockIdx.x * 64;
    const int n0 = blockIdx.y * 64;
    const int l15 = lane & 15;
    const int lhi = lane >> 4;                   // 0..3
    f32x4 acc[4] = {};

    for (int kt0 = 0; kt0 < K; kt0 += BK) {
        #pragma unroll
        for (int it = 0; it < 4; ++it) {
            int idx = it * 256 + tid;
            int row = idx >> 4;
            int c8  = (idx & 15) << 3;
            uint4 v = make_uint4(0u, 0u, 0u, 0u);
            if (m0 + row < M)
                v = *(const uint4*)&A[(size_t)(m0 + row) * K + kt0 + c8];
            *(uint4*)&As[row * LDK + c8] = v;
        }
        #pragma unroll
        for (int it = 0; it < 4; ++it) {
            int idx = it * 256 + tid;
            int nrow = idx >> 4;
            int c8   = (idx & 15) << 3;
            uint4 v = *(const uint4*)&Wt[(size_t)(n0 + nrow) * K + kt0 + c8];
            *(uint4*)&Ws[nrow * LDK + c8] = v;
        }
        __syncthreads();

        #pragma unroll
        for (int kk = 0; kk < BK; kk += 32) {
            bf16x8 a = *(const bf16x8*)&As[(w * 16 + l15) * LDK + kk + lhi * 8];
            #pragma unroll
            for (int nt = 0; nt < 4; ++nt) {
                bf16x8 b = *(const bf16x8*)&Ws[(nt * 16 + l15) * LDK + kk + lhi * 8];
                acc[nt] = __builtin_amdgcn_mfma_f32_16x16x32_bf16(a, b, acc[nt], 0, 0, 0);
            }
        }
        __syncthreads();
    }

    #pragma unroll
    for (int nt = 0; nt < 4; ++nt) {
        int col = n0 + nt * 16 + l15;
        float bz = bias[col];
        #pragma unroll
        for (int r = 0; r < 4; ++r) {
            int row = m0 + w * 16 + lhi * 4 + r;
            if (row < M) {
                float v = acc[nt][r] + bz;
                if (MASK_LEAKY) {
                    int deg = iend[row] - istart[row];
                    v = (deg == 0) ? 0.f : (v > 0.f ? v : 0.01f * v);
                }
                C[(size_t)row * N + col] = (unsigned short)bf16rne(v);
            }
        }
    }
}

// ---------------- f32 VALU GEMM (ws-fallback path only) ---------------------

template<int K, int N, bool MASK_LEAKY, bool BF16_OUT>
__global__ __launch_bounds__(256) void gemm_kernel(const float* __restrict__ A,
                                                   const float* __restrict__ W,
                                                   const float* __restrict__ bias,
                                                   const int* __restrict__ istart,
                                                   const int* __restrict__ iend,
                                                   void* __restrict__ Cout, int M) {
    __shared__ float As[64 * 68];
    __shared__ float Ws[64 * 64];
    const int tid = threadIdx.x;
    const int tx = tid & 15, ty = tid >> 4;
    const int m0 = blockIdx.x * 64;
    const int n0 = blockIdx.y * 64;
    const int r0 = ty << 2, c0 = tx << 2;
    float acc[4][4] = {};

    for (int kt = 0; kt < K; kt += 64) {
        #pragma unroll
        for (int q = 0; q < 4; ++q) {
            int idx = tid + q * 256;
            int row = idx >> 4;
            int c4  = (idx & 15) << 2;
            float4 v = make_float4(0.f, 0.f, 0.f, 0.f);
            if (m0 + row < M)
                v = *(const float4*)&A[(size_t)(m0 + row) * K + kt + c4];
            *(float4*)&As[row * 68 + c4] = v;
        }
        #pragma unroll
        for (int q = 0; q < 4; ++q) {
            int idx = tid + q * 256;
            int k   = idx >> 4;
            int c4  = (idx & 15) << 2;
            *(float4*)&Ws[(k << 6) + c4] =
                *(const float4*)&W[(size_t)(kt + k) * N + n0 + c4];
        }
        __syncthreads();

        #pragma unroll 4
        for (int k = 0; k < 64; k += 4) {
            float a[4][4];
            #pragma unroll
            for (int r = 0; r < 4; ++r) {
                float4 v = *(const float4*)&As[(r0 + r) * 68 + k];
                a[r][0] = v.x; a[r][1] = v.y; a[r][2] = v.z; a[r][3] = v.w;
            }
            #pragma unroll
            for (int kk = 0; kk < 4; ++kk) {
                float4 w = *(const float4*)&Ws[((k + kk) << 6) + c0];
                #pragma unroll
                for (int r = 0; r < 4; ++r) {
                    acc[r][0] = fmaf(a[r][kk], w.x, acc[r][0]);
                    acc[r][1] = fmaf(a[r][kk], w.y, acc[r][1]);
                    acc[r][2] = fmaf(a[r][kk], w.z, acc[r][2]);
                    acc[r][3] = fmaf(a[r][kk], w.w, acc[r][3]);
                }
            }
        }
        __syncthreads();
    }

    float4 b = *(const float4*)&bias[n0 + c0];
    #pragma unroll
    for (int r = 0; r < 4; ++r) {
        int row = m0 + r0 + r;
        if (row < M) {
            float4 v;
            v.x = acc[r][0] + b.x; v.y = acc[r][1] + b.y;
            v.z = acc[r][2] + b.z; v.w = acc[r][3] + b.w;
            if (MASK_LEAKY) {
                int deg = iend[row] - istart[row];
                if (deg == 0) {
                    v = make_float4(0.f, 0.f, 0.f, 0.f);
                } else {
                    v.x = v.x > 0.f ? v.x : 0.01f * v.x;
                    v.y = v.y > 0.f ? v.y : 0.01f * v.y;
                    v.z = v.z > 0.f ? v.z : 0.01f * v.z;
                    v.w = v.w > 0.f ? v.w : 0.01f * v.w;
                }
            }
            if (BF16_OUT) {
                uint2 w;
                w.x = bf16rne(v.x) | (bf16rne(v.y) << 16);
                w.y = bf16rne(v.z) | (bf16rne(v.w) << 16);
                *(uint2*)&((unsigned short*)Cout)[(size_t)row * N + n0 + c0] = w;
            } else {
                *(float4*)&((float*)Cout)[(size_t)row * N + n0 + c0] = v;
            }
        }
    }
}

// ---------------- launch ----------------

extern "C" void kernel_launch(void* const* d_in, const int* in_sizes, int n_in,
                              void* d_out, int out_size, void* d_ws, size_t ws_size,
                              hipStream_t stream) {
    const int*   src_cg     = (const int*)d_in[0];
    const int*   dst_cg     = (const int*)d_in[1];
    const int*   src_gc     = (const int*)d_in[2];
    const int*   dst_gc     = (const int*)d_in[3];
    const float* embed_chem = (const float*)d_in[4];
    const float* W1_cg = (const float*)d_in[6];
    const float* b1_cg = (const float*)d_in[7];
    const float* W2_gc = (const float*)d_in[12];
    const float* b2_gc = (const float*)d_in[13];
    float* out = (float*)d_out;

    // workspace layout (int words)
    int* ws_i = (int*)d_ws;
    size_t off = 0;
    int* bcur   = ws_i + off; off += NB;         // zeroed each launch
    int* istart = ws_i + off; off += N_SEG;
    int* iend   = ws_i + off; off += N_SEG;
    off = (off + 3) & ~(size_t)3;
    int* esrc   = ws_i + off; off += (size_t)NB * CAP;   // CAP-strided (23 MB)
    // records (NB*CAP ints) is dead before agg1/h_gene are written -> overlay
    size_t union_off = off;
    unsigned* records = (unsigned*)(ws_i + union_off);
    unsigned short* agg1b   = (unsigned short*)(ws_i + union_off);
    unsigned short* h_geneb = agg1b + (size_t)N_GENE * IN_D;
    float* agg1f   = (float*)(ws_i + union_off);
    float* h_genef = agg1f + (size_t)N_GENE * IN_D;
    size_t union_sz = (size_t)NB * CAP;                  // 5.77M ints
    if (union_sz < (size_t)N_GENE * (IN_D + HID_D)) union_sz = (size_t)N_GENE * (IN_D + HID_D);
    off = union_off + union_sz;
    unsigned short* Wh2b = (unsigned short*)(ws_i + off); off += (size_t)N_GENE * OUT_D / 2;
    unsigned short* embedb = (unsigned short*)(ws_i + off); off += (size_t)N_CHEM * IN_D / 2;
    unsigned short* W1t = (unsigned short*)(ws_i + off); off += (size_t)HID_D * IN_D / 2;
    unsigned short* W2t = (unsigned short*)(ws_i + off); off += (size_t)OUT_D * HID_D / 2;
    const bool bf16_embed = ws_size >= off * sizeof(int);        // launch-constant

    (void)hipMemsetAsync(bcur, 0, NB * sizeof(int), stream);

    // ---- CSR build + (overlapped) embed conversion + weight transpose
    const int nextra = bf16_embed ? (NCONV + NWT) : 0;
    place_convert_kernel<<<NBA + nextra, 256, 0, stream>>>(
        src_cg, dst_cg, src_gc, dst_gc, bcur, records, embed_chem, embedb,
        W1_cg, W2_gc, W1t, W2t);
    bin_b_kernel<<<NB, 256, 0, stream>>>(records, bcur, istart, iend, esrc);

    if (bf16_embed) {
        // layer 1 aggregate (mean is linear; project after), bf16 output
        gather_mean_bf16_split_kernel<<<(N_GENE + 7) / 8, 256, 0, stream>>>(
            embedb, istart, iend, esrc, agg1b, N_GENE);
        // h_gene(bf16) = deg>0 ? leaky(agg1 @ W1 + b1) : 0   [MFMA, Wt staged]
        {
            dim3 g((N_GENE + 63) / 64, HID_D / 64), blk(256);
            gemm_mfma_kernel<IN_D, HID_D, true><<<g, blk, 0, stream>>>(
                agg1b, W1t, b1_cg, istart, iend, h_geneb, N_GENE);
        }
        // Wh2(bf16) = h_gene @ W2 + b2   [MFMA, Wt staged]
        {
            dim3 g((N_GENE + 63) / 64, OUT_D / 64), blk(256);
            gemm_mfma_kernel<HID_D, OUT_D, false><<<g, blk, 0, stream>>>(
                h_geneb, W2t, b2_gc, istart, iend, Wh2b, N_GENE);
        }
    } else {
        gather_mean_f32_kernel<<<(N_GENE + 7) / 8, 256, 0, stream>>>(
            embed_chem, istart, iend, esrc, agg1f, N_GENE);
        {
            dim3 g((N_GENE + 63) / 64, HID_D / 64), blk(256);
            gemm_kernel<IN_D, HID_D, true, false><<<g, blk, 0, stream>>>(
                agg1f, W1_cg, b1_cg, istart, iend, h_genef, N_GENE);
        }
        {
            dim3 g((N_GENE + 63) / 64, OUT_D / 64), blk(256);
            gemm_kernel<HID_D, OUT_D, false, true><<<g, blk, 0, stream>>>(
                h_genef, W2_gc, b2_gc, istart, iend, Wh2b, N_GENE);
        }
    }

    // out = seg_mean(Wh2[src_gc], dst_gc, N_CHEM)  (chem segments start at N_GENE)
    gather_mean_bf16_kernel<true><<<(N_CHEM + 15) / 16, 256, 0, stream>>>(
        Wh2b, istart + N_GENE, iend + N_GENE, esrc, out, N_CHEM);
}

// Round 11
// 328.933 us; speedup vs baseline: 1.1581x; 1.0071x over previous
//
#include <hip/hip_runtime.h>
#include <stdint.h>
#include <stddef.h>

#define N_CHEM 200000
#define N_GENE 20000
#define N_EDGES 1000000
#define IN_D 128
#define HID_D 256
#define OUT_D 128
#define N_SEG (N_GENE + N_CHEM)          // 220000 concatenated segments

// ---- bucket decomposition of the segment space -----------------------------
#define NGB 313
#define NCB 391
#define NB  (NGB + NCB)                  // 704
#define EPB 4096                         // r4/r8-measured best
#define NBA ((2 * N_EDGES + EPB - 1) / EPB)   // 489 place blocks
#define NCONV 6250                       // embed-convert blocks (bf16 path)
#define NWT 16                           // weight transpose blocks (8 W1 + 8 W2)
#define NGGB ((N_GENE + 7) / 8)          // 2500 gene-gather blocks
#define CAP 8192                         // per-bucket capacity (exp<=3500)
#define DROPPED 0x80000000               // overflow sentinel (never hit)

typedef float nfloat4 __attribute__((ext_vector_type(4)));   // native vec for NT store
typedef __attribute__((ext_vector_type(8))) short bf16x8;    // 8 bf16 = 4 VGPRs
typedef __attribute__((ext_vector_type(4))) float f32x4;

__device__ inline unsigned bf16rne(float x) {
    unsigned u = __float_as_uint(x);
    return (u + 0x7FFFu + ((u >> 16) & 1u)) >> 16;
}

__device__ inline int bucket_of(int slot) {
    return (slot < N_GENE) ? (slot >> 6) : (NGB + ((slot - N_GENE) >> 9));
}
__device__ inline int bucket_slot0(int b) {
    return (b < NGB) ? (b << 6) : (N_GENE + ((b - NGB) << 9));
}

// ---------------- CSR build ------------------------------------------------
// Pass A (fused): [0,NBA) scatter packed (local_slot<<18|src) records into
// fixed-capacity bucket regions (LDS-ordered -> coalesced run writes);
// [NBA,NBA+NCONV) f32->bf16 embed conversion; [NBA+NCONV,+NWT) weight
// transpose+convert. Measured notes: place path is the ~60us critical path
// (convert hides inside); same time at 4 and 5 blk/CU (not occupancy-bound);
// r7: column-slicing = 2x FETCH (128B granule, blockIdx !~ XCD); r5:
// per-block __threadfence = 100us; r9: scalar cvt LDS staging = 2.7M conflicts.

__global__ __launch_bounds__(256) void place_convert_kernel(
        const int* __restrict__ src_cg, const int* __restrict__ dst_cg,
        const int* __restrict__ src_gc, const int* __restrict__ dst_gc,
        int* __restrict__ bcur, unsigned* __restrict__ records,
        const float* __restrict__ conv_in, unsigned short* __restrict__ conv_out,
        const float* __restrict__ W1, const float* __restrict__ W2,
        unsigned short* __restrict__ W1t, unsigned short* __restrict__ W2t) {
    __shared__ unsigned stage_rec[EPB];        // 16 KB packed records (reused as tile)
    __shared__ unsigned short stage_bkt[EPB];  // 8 KB bucket ids
    __shared__ int hist[NB];
    __shared__ int cursor[NB];
    __shared__ int tsum[256];
    const int tid = threadIdx.x;
    const int bid = blockIdx.x;

    if (bid >= NBA + NCONV) {
        // ---- weight transpose path: one 64x64 tile per block ----
        unsigned short* tile = (unsigned short*)stage_rec;   // [64][65]
        int wb = bid - NBA - NCONV;
        const float* Wsrc; unsigned short* Wdst; int K, N, kt0, n0;
        if (wb < 8) { Wsrc = W1; Wdst = W1t; K = 128; N = 256;
                      kt0 = (wb >> 2) * 64; n0 = (wb & 3) * 64; }
        else        { wb -= 8; Wsrc = W2; Wdst = W2t; K = 256; N = 128;
                      kt0 = (wb >> 1) * 64; n0 = (wb & 1) * 64; }
        #pragma unroll
        for (int it = 0; it < 16; ++it) {
            int idx = it * 256 + tid;
            int r = idx >> 6, c = idx & 63;
            tile[c * 65 + r] = (unsigned short)bf16rne(Wsrc[(size_t)(kt0 + r) * N + n0 + c]);
        }
        __syncthreads();
        #pragma unroll
        for (int it = 0; it < 16; ++it) {
            int idx = it * 256 + tid;
            int r = idx >> 6, c = idx & 63;
            Wdst[(size_t)(n0 + r) * K + kt0 + c] = tile[r * 65 + c];
        }
        return;
    }
    if (bid >= NBA) {
        // ---- embed conversion path: 1024 float4 per block ----
        int cb = bid - NBA;
        #pragma unroll
        for (int q = 0; q < 4; ++q) {
            int i = cb * 1024 + q * 256 + tid;
            if (i < N_CHEM * IN_D / 4) {
                float4 v = *(const float4*)&conv_in[(size_t)i * 4];
                uint2 w;
                w.x = bf16rne(v.x) | (bf16rne(v.y) << 16);
                w.y = bf16rne(v.z) | (bf16rne(v.w) << 16);
                *(uint2*)&conv_out[(size_t)i * 4] = w;
            }
        }
        return;
    }
    // ---- place path ----
    const int e0 = bid * EPB;
    const int cnt_blk = min(EPB, 2 * N_EDGES - e0);

    for (int i = tid; i < NB; i += 256) hist[i] = 0;
    __syncthreads();

    int slotR[EPB / 256], srcR[EPB / 256];
    #pragma unroll
    for (int q = 0; q < EPB / 256; ++q) {
        int e = e0 + q * 256 + tid;
        int slot = -1, s = 0;
        if (e < N_EDGES)            { slot = dst_cg[e];                    s = src_cg[e]; }
        else if (e < 2 * N_EDGES)   { slot = N_GENE + dst_gc[e - N_EDGES]; s = src_gc[e - N_EDGES]; }
        slotR[q] = slot; srcR[q] = s;
        if (slot >= 0) atomicAdd(&hist[bucket_of(slot)], 1);
    }
    __syncthreads();

    const int b3 = tid * 3;
    int h0 = (b3     < NB) ? hist[b3]     : 0;
    int h1 = (b3 + 1 < NB) ? hist[b3 + 1] : 0;
    int h2 = (b3 + 2 < NB) ? hist[b3 + 2] : 0;
    int ts = h0 + h1 + h2;
    tsum[tid] = ts;
    __syncthreads();
    for (int off = 1; off < 256; off <<= 1) {
        int t = (tid >= off) ? tsum[tid - off] : 0;
        __syncthreads();
        tsum[tid] += t;
        __syncthreads();
    }
    int base = tsum[tid] - ts;
    if (b3     < NB) cursor[b3]     = base;
    if (b3 + 1 < NB) cursor[b3 + 1] = base + h0;
    if (b3 + 2 < NB) cursor[b3 + 2] = base + h0 + h1;
    __syncthreads();

    #pragma unroll
    for (int q = 0; q < EPB / 256; ++q) {
        int slot = slotR[q];
        if (slot >= 0) {
            int b = bucket_of(slot);
            int p = atomicAdd(&cursor[b], 1);
            stage_rec[p] = ((unsigned)(slot - bucket_slot0(b)) << 18) | (unsigned)srcR[q];
            stage_bkt[p] = (unsigned short)b;
        }
    }
    __syncthreads();

    for (int i = tid; i < NB; i += 256) {
        int n = hist[i];
        if (n) {
            int got = atomicAdd(&bcur[i], n);
            int excl_i = cursor[i] - n;          // cursor is now excl+n
            hist[i] = (got + n <= CAP) ? (i * CAP + got - excl_i) : (int)DROPPED;
        }
    }
    __syncthreads();

    for (int i = tid; i < cnt_blk; i += 256) {
        int d = hist[stage_bkt[i]];
        if (d != (int)DROPPED) records[i + d] = stage_rec[i];
    }
}

// bin_b body (shared by the gene-only dispatch and the fused chem path):
// one block per bucket -> local histogram+scan -> istart/iend + esrc.

__device__ __forceinline__ void bin_b_body(
        int b, const unsigned* __restrict__ records, const int* __restrict__ bcur,
        int* __restrict__ istart, int* __restrict__ iend, int* __restrict__ esrc,
        int* hist, int* tsum) {
    const int tid = threadIdx.x;
    int slot0 = bucket_slot0(b);
    int nslots = (b < NGB) ? min(64, N_GENE - slot0) : min(512, N_SEG - slot0);
    const int rbase = b * CAP;
    const int E = min(bcur[b], CAP);
    const unsigned* rec = &records[(size_t)b * CAP];

    hist[tid] = 0; hist[tid + 256] = 0;
    __syncthreads();
    for (int i = tid; i < E; i += 256)
        atomicAdd(&hist[rec[i] >> 18], 1);
    __syncthreads();

    int h0 = hist[2 * tid], h1 = hist[2 * tid + 1];
    int ts = h0 + h1;
    tsum[tid] = ts;
    __syncthreads();
    for (int off = 1; off < 256; off <<= 1) {
        int t = (tid >= off) ? tsum[tid - off] : 0;
        __syncthreads();
        tsum[tid] += t;
        __syncthreads();
    }
    int ex = tsum[tid] - ts;
    __syncthreads();
    hist[2 * tid]     = ex;              // becomes the placement cursor
    hist[2 * tid + 1] = ex + h0;
    if (2 * tid < nslots) {
        istart[slot0 + 2 * tid] = rbase + ex;
        iend[slot0 + 2 * tid]   = rbase + ex + h0;
    }
    if (2 * tid + 1 < nslots) {
        istart[slot0 + 2 * tid + 1] = rbase + ex + h0;
        iend[slot0 + 2 * tid + 1]   = rbase + ex + h0 + h1;
    }
    __syncthreads();

    for (int i = tid; i < E; i += 256) {
        unsigned r = rec[i];
        int p = atomicAdd(&hist[r >> 18], 1);
        esrc[rbase + p] = (int)(r & 0x3FFFFu);
    }
}

__global__ __launch_bounds__(256) void bin_b_kernel(
        const unsigned* __restrict__ records, const int* __restrict__ bcur,
        int* __restrict__ istart, int* __restrict__ iend, int* __restrict__ esrc) {
    __shared__ int hist[512];
    __shared__ int tsum[256];
    bin_b_body(blockIdx.x, records, bcur, istart, iend, esrc, hist, tsum);
}

// ---------------- gather-mean over a bf16 table -----------------------------

__device__ inline void acc_u(float* a, uint4 v) {
    a[0] += __uint_as_float(v.x << 16); a[1] += __uint_as_float(v.x & 0xffff0000u);
    a[2] += __uint_as_float(v.y << 16); a[3] += __uint_as_float(v.y & 0xffff0000u);
    a[4] += __uint_as_float(v.z << 16); a[5] += __uint_as_float(v.z & 0xffff0000u);
    a[6] += __uint_as_float(v.w << 16); a[7] += __uint_as_float(v.w & 0xffff0000u);
}

// Fused: blocks [0,NCB) bin the CHEM buckets (hidden under the latency-bound
// gene gather, which only needs GENE buckets -- binned by the prior 313-block
// dispatch); blocks [NCB,NCB+NGGB) gene-gather (r6/r8-measured config:
// 32 lanes/node, 2 edge-list halves, 8-deep unroll, bf16 packed output).
// Aliasing: chem-bin reads records ints >= 313*CAP=2.56M; gather writes agg1b
// ints [0,1.28M) -- disjoint (gene records are dead after the gene bin pass).

__global__ __launch_bounds__(256) void gather_gene_chembin_kernel(
        const unsigned short* __restrict__ table,
        const int* __restrict__ esrc_ro,
        unsigned short* __restrict__ outb, int n,
        const unsigned* __restrict__ records, const int* __restrict__ bcur,
        int* __restrict__ istart, int* __restrict__ iend, int* __restrict__ esrc_w) {
    __shared__ int hist[512];
    __shared__ int tsum[256];
    if ((int)blockIdx.x < NCB) {
        bin_b_body(NGB + blockIdx.x, records, bcur, istart, iend, esrc_w, hist, tsum);
        return;
    }
    int lane = threadIdx.x & 15;             // col group
    int half = (threadIdx.x >> 4) & 1;       // edge-list half
    int node = (blockIdx.x - NCB) * 8 + (threadIdx.x >> 5);
    if (node >= n) return;
    int s = istart[node], e = iend[node];
    int deg = e - s;
    int mid = s + ((deg + 1) >> 1);
    int j0 = half ? mid : s;
    int j1 = half ? e   : mid;
    int c = lane << 3;                       // 8 cols per lane
    float acc[8] = {};
    int j = j0;
    for (; j + 8 <= j1; j += 8) {
        int i0 = esrc_ro[j],     i1 = esrc_ro[j + 1], i2 = esrc_ro[j + 2], i3 = esrc_ro[j + 3];
        int i4 = esrc_ro[j + 4], i5 = esrc_ro[j + 5], i6 = esrc_ro[j + 6], i7 = esrc_ro[j + 7];
        uint4 v0 = *(const uint4*)&table[(size_t)i0 * 128 + c];
        uint4 v1 = *(const uint4*)&table[(size_t)i1 * 128 + c];
        uint4 v2 = *(const uint4*)&table[(size_t)i2 * 128 + c];
        uint4 v3 = *(const uint4*)&table[(size_t)i3 * 128 + c];
        uint4 v4 = *(const uint4*)&table[(size_t)i4 * 128 + c];
        uint4 v5 = *(const uint4*)&table[(size_t)i5 * 128 + c];
        uint4 v6 = *(const uint4*)&table[(size_t)i6 * 128 + c];
        uint4 v7 = *(const uint4*)&table[(size_t)i7 * 128 + c];
        acc_u(acc, v0); acc_u(acc, v1); acc_u(acc, v2); acc_u(acc, v3);
        acc_u(acc, v4); acc_u(acc, v5); acc_u(acc, v6); acc_u(acc, v7);
    }
    for (; j + 4 <= j1; j += 4) {
        uint4 v0 = *(const uint4*)&table[(size_t)esrc_ro[j]     * 128 + c];
        uint4 v1 = *(const uint4*)&table[(size_t)esrc_ro[j + 1] * 128 + c];
        uint4 v2 = *(const uint4*)&table[(size_t)esrc_ro[j + 2] * 128 + c];
        uint4 v3 = *(const uint4*)&table[(size_t)esrc_ro[j + 3] * 128 + c];
        acc_u(acc, v0); acc_u(acc, v1); acc_u(acc, v2); acc_u(acc, v3);
    }
    for (; j < j1; ++j) {
        uint4 v = *(const uint4*)&table[(size_t)esrc_ro[j] * 128 + c];
        acc_u(acc, v);
    }
    #pragma unroll
    for (int q = 0; q < 8; ++q) acc[q] += __shfl_xor(acc[q], 16);
    if (half == 0) {
        float inv = (deg > 0) ? 1.f / (float)deg : 0.f;
        #pragma unroll
        for (int q = 0; q < 8; ++q) acc[q] *= inv;
        uint4 w;
        w.x = bf16rne(acc[0]) | (bf16rne(acc[1]) << 16);
        w.y = bf16rne(acc[2]) | (bf16rne(acc[3]) << 16);
        w.z = bf16rne(acc[4]) | (bf16rne(acc[5]) << 16);
        w.w = bf16rne(acc[6]) | (bf16rne(acc[7]) << 16);
        *(uint4*)&outb[(size_t)node * 128 + c] = w;
    }
}

// Chem-side gather (r6/r8-measured): 16 lanes/node, deg ~5, f32 NT output.

template<bool NT>
__global__ __launch_bounds__(256) void gather_mean_bf16_kernel(
        const unsigned short* __restrict__ table,
        const int* __restrict__ istart, const int* __restrict__ iend,
        const int* __restrict__ esrc,
        float* __restrict__ out, int n) {
    int lane = threadIdx.x & 15;
    int node = blockIdx.x * 16 + (threadIdx.x >> 4);
    if (node >= n) return;
    int s = istart[node], e = iend[node];
    int c = lane << 3;                       // 8 cols per lane
    float acc[8] = {};
    int j = s;
    for (; j + 4 <= e; j += 4) {
        uint4 v0 = *(const uint4*)&table[(size_t)esrc[j]     * 128 + c];
        uint4 v1 = *(const uint4*)&table[(size_t)esrc[j + 1] * 128 + c];
        uint4 v2 = *(const uint4*)&table[(size_t)esrc[j + 2] * 128 + c];
        uint4 v3 = *(const uint4*)&table[(size_t)esrc[j + 3] * 128 + c];
        acc_u(acc, v0); acc_u(acc, v1); acc_u(acc, v2); acc_u(acc, v3);
    }
    for (; j < e; ++j) {
        uint4 v = *(const uint4*)&table[(size_t)esrc[j] * 128 + c];
        acc_u(acc, v);
    }
    int deg = e - s;
    float inv = (deg > 0) ? 1.f / (float)deg : 0.f;
    #pragma unroll
    for (int q = 0; q < 8; ++q) acc[q] *= inv;
    float* dst = &out[(size_t)node * 128 + c];
    if (NT) {
        nfloat4 a = { acc[0], acc[1], acc[2], acc[3] };
        nfloat4 b = { acc[4], acc[5], acc[6], acc[7] };
        __builtin_nontemporal_store(a, (nfloat4*)dst);
        __builtin_nontemporal_store(b, (nfloat4*)(dst + 4));
    } else {
        *(float4*)dst       = make_float4(acc[0], acc[1], acc[2], acc[3]);
        *(float4*)(dst + 4) = make_float4(acc[4], acc[5], acc[6], acc[7]);
    }
}

// ---------------- gather-mean over an f32 table (ws-fallback path) ----------

__global__ __launch_bounds__(256) void gather_mean_f32_kernel(
        const float* __restrict__ table,
        const int* __restrict__ istart, const int* __restrict__ iend,
        const int* __restrict__ esrc,
        float* __restrict__ out, int n) {
    int lane = threadIdx.x & 31;
    int node = blockIdx.x * 8 + (threadIdx.x >> 5);
    if (node >= n) return;
    int s = istart[node], e = iend[node];
    int c = lane << 2;
    float4 acc = make_float4(0.f, 0.f, 0.f, 0.f);
    int j = s;
    for (; j + 4 <= e; j += 4) {
        int s0 = esrc[j], s1 = esrc[j + 1], s2 = esrc[j + 2], s3 = esrc[j + 3];
        float4 v0 = *(const float4*)&table[(size_t)s0 * 128 + c];
        float4 v1 = *(const float4*)&table[(size_t)s1 * 128 + c];
        float4 v2 = *(const float4*)&table[(size_t)s2 * 128 + c];
        float4 v3 = *(const float4*)&table[(size_t)s3 * 128 + c];
        acc.x += (v0.x + v1.x) + (v2.x + v3.x);
        acc.y += (v0.y + v1.y) + (v2.y + v3.y);
        acc.z += (v0.z + v1.z) + (v2.z + v3.z);
        acc.w += (v0.w + v1.w) + (v2.w + v3.w);
    }
    for (; j < e; ++j) {
        float4 v = *(const float4*)&table[(size_t)esrc[j] * 128 + c];
        acc.x += v.x; acc.y += v.y; acc.z += v.z; acc.w += v.w;
    }
    int deg = e - s;
    float inv = (deg > 0) ? 1.f / (float)deg : 0.f;
    acc.x *= inv; acc.y *= inv; acc.z *= inv; acc.w *= inv;
    *(float4*)&out[(size_t)node * 128 + c] = acc;
}

// ---------------- bf16 MFMA GEMM: C[M,N](bf16) = A[M,K](bf16) @ Wt^T + bias -
// Wt is PRE-TRANSPOSED bf16 [N][K] (r10 fix: W staging = coalesced uint4 +
// ds_write_b128, same as A stage; r9's scalar staging = 2.7M bank conflicts).

template<int K, int N, bool MASK_LEAKY>
__global__ __launch_bounds__(256) void gemm_mfma_kernel(
        const unsigned short* __restrict__ A,    // [M][K] bf16
        const unsigned short* __restrict__ Wt,   // [N][K] bf16 (transposed)
        const float* __restrict__ bias,          // [N] f32
        const int* __restrict__ istart, const int* __restrict__ iend,
        unsigned short* __restrict__ C,          // [M][N] bf16
        int M) {
    constexpr int BK  = 128;
    constexpr int LDK = BK + 8;                  // +16B pad
    __shared__ unsigned short As[64 * LDK];      // 17 KB
    __shared__ unsigned short Ws[64 * LDK];      // 17 KB: Ws[n][k]
    const int tid  = threadIdx.x;
    const int lane = tid & 63;
    const int w    = tid >> 6;                   // wave: output rows w*16..+15
    const int m0 = blockIdx.x * 64;
    const int n0 = blockIdx.y * 64;
    const int l15 = lane & 15;
    const int lhi = lane >> 4;                   // 0..3
    f32x4 acc[4] = {};

    for (int kt0 = 0; kt0 < K; kt0 += BK) {
        #pragma unroll
        for (int it = 0; it < 4; ++it) {
            int idx = it * 256 + tid;
            int row = idx >> 4;
            int c8  = (idx & 15) << 3;
            uint4 v = make_uint4(0u, 0u, 0u, 0u);
            if (m0 + row < M)
                v = *(const uint4*)&A[(size_t)(m0 + row) * K + kt0 + c8];
            *(uint4*)&As[row * LDK + c8] = v;
        }
        #pragma unroll
        for (int it = 0; it < 4; ++it) {
            int idx = it * 256 + tid;
            int nrow = idx >> 4;
            int c8   = (idx & 15) << 3;
            uint4 v = *(const uint4*)&Wt[(size_t)(n0 + nrow) * K + kt0 + c8];
            *(uint4*)&Ws[nrow * LDK + c8] = v;
        }
        __syncthreads();

        #pragma unroll
        for (int kk = 0; kk < BK; kk += 32) {
            bf16x8 a = *(const bf16x8*)&As[(w * 16 + l15) * LDK + kk + lhi * 8];
            #pragma unroll
            for (int nt = 0; nt < 4; ++nt) {
                bf16x8 b = *(const bf16x8*)&Ws[(nt * 16 + l15) * LDK + kk + lhi * 8];
                acc[nt] = __builtin_amdgcn_mfma_f32_16x16x32_bf16(a, b, acc[nt], 0, 0, 0);
            }
        }
        __syncthreads();
    }

    #pragma unroll
    for (int nt = 0; nt < 4; ++nt) {
        int col = n0 + nt * 16 + l15;
        float bz = bias[col];
        #pragma unroll
        for (int r = 0; r < 4; ++r) {
            int row = m0 + w * 16 + lhi * 4 + r;
            if (row < M) {
                float v = acc[nt][r] + bz;
                if (MASK_LEAKY) {
                    int deg = iend[row] - istart[row];
                    v = (deg == 0) ? 0.f : (v > 0.f ? v : 0.01f * v);
                }
                C[(size_t)row * N + col] = (unsigned short)bf16rne(v);
            }
        }
    }
}

// ---------------- f32 VALU GEMM (ws-fallback path only) ---------------------

template<int K, int N, bool MASK_LEAKY, bool BF16_OUT>
__global__ __launch_bounds__(256) void gemm_kernel(const float* __restrict__ A,
                                                   const float* __restrict__ W,
                                                   const float* __restrict__ bias,
                                                   const int* __restrict__ istart,
                                                   const int* __restrict__ iend,
                                                   void* __restrict__ Cout, int M) {
    __shared__ float As[64 * 68];
    __shared__ float Ws[64 * 64];
    const int tid = threadIdx.x;
    const int tx = tid & 15, ty = tid >> 4;
    const int m0 = blockIdx.x * 64;
    const int n0 = blockIdx.y * 64;
    const int r0 = ty << 2, c0 = tx << 2;
    float acc[4][4] = {};

    for (int kt = 0; kt < K; kt += 64) {
        #pragma unroll
        for (int q = 0; q < 4; ++q) {
            int idx = tid + q * 256;
            int row = idx >> 4;
            int c4  = (idx & 15) << 2;
            float4 v = make_float4(0.f, 0.f, 0.f, 0.f);
            if (m0 + row < M)
                v = *(const float4*)&A[(size_t)(m0 + row) * K + kt + c4];
            *(float4*)&As[row * 68 + c4] = v;
        }
        #pragma unroll
        for (int q = 0; q < 4; ++q) {
            int idx = tid + q * 256;
            int k   = idx >> 4;
            int c4  = (idx & 15) << 2;
            *(float4*)&Ws[(k << 6) + c4] =
                *(const float4*)&W[(size_t)(kt + k) * N + n0 + c4];
        }
        __syncthreads();

        #pragma unroll 4
        for (int k = 0; k < 64; k += 4) {
            float a[4][4];
            #pragma unroll
            for (int r = 0; r < 4; ++r) {
                float4 v = *(const float4*)&As[(r0 + r) * 68 + k];
                a[r][0] = v.x; a[r][1] = v.y; a[r][2] = v.z; a[r][3] = v.w;
            }
            #pragma unroll
            for (int kk = 0; kk < 4; ++kk) {
                float4 w = *(const float4*)&Ws[((k + kk) << 6) + c0];
                #pragma unroll
                for (int r = 0; r < 4; ++r) {
                    acc[r][0] = fmaf(a[r][kk], w.x, acc[r][0]);
                    acc[r][1] = fmaf(a[r][kk], w.y, acc[r][1]);
                    acc[r][2] = fmaf(a[r][kk], w.z, acc[r][2]);
                    acc[r][3] = fmaf(a[r][kk], w.w, acc[r][3]);
                }
            }
        }
        __syncthreads();
    }

    float4 b = *(const float4*)&bias[n0 + c0];
    #pragma unroll
    for (int r = 0; r < 4; ++r) {
        int row = m0 + r0 + r;
        if (row < M) {
            float4 v;
            v.x = acc[r][0] + b.x; v.y = acc[r][1] + b.y;
            v.z = acc[r][2] + b.z; v.w = acc[r][3] + b.w;
            if (MASK_LEAKY) {
                int deg = iend[row] - istart[row];
                if (deg == 0) {
                    v = make_float4(0.f, 0.f, 0.f, 0.f);
                } else {
                    v.x = v.x > 0.f ? v.x : 0.01f * v.x;
                    v.y = v.y > 0.f ? v.y : 0.01f * v.y;
                    v.z = v.z > 0.f ? v.z : 0.01f * v.z;
                    v.w = v.w > 0.f ? v.w : 0.01f * v.w;
                }
            }
            if (BF16_OUT) {
                uint2 w;
                w.x = bf16rne(v.x) | (bf16rne(v.y) << 16);
                w.y = bf16rne(v.z) | (bf16rne(v.w) << 16);
                *(uint2*)&((unsigned short*)Cout)[(size_t)row * N + n0 + c0] = w;
            } else {
                *(float4*)&((float*)Cout)[(size_t)row * N + n0 + c0] = v;
            }
        }
    }
}

// ---------------- launch ----------------

extern "C" void kernel_launch(void* const* d_in, const int* in_sizes, int n_in,
                              void* d_out, int out_size, void* d_ws, size_t ws_size,
                              hipStream_t stream) {
    const int*   src_cg     = (const int*)d_in[0];
    const int*   dst_cg     = (const int*)d_in[1];
    const int*   src_gc     = (const int*)d_in[2];
    const int*   dst_gc     = (const int*)d_in[3];
    const float* embed_chem = (const float*)d_in[4];
    const float* W1_cg = (const float*)d_in[6];
    const float* b1_cg = (const float*)d_in[7];
    const float* W2_gc = (const float*)d_in[12];
    const float* b2_gc = (const float*)d_in[13];
    float* out = (float*)d_out;

    // workspace layout (int words)
    int* ws_i = (int*)d_ws;
    size_t off = 0;
    int* bcur   = ws_i + off; off += NB;         // zeroed each launch
    int* istart = ws_i + off; off += N_SEG;
    int* iend   = ws_i + off; off += N_SEG;
    off = (off + 3) & ~(size_t)3;
    int* esrc   = ws_i + off; off += (size_t)NB * CAP;   // CAP-strided (23 MB)
    // records (NB*CAP ints) is dead (per-bucket) before the overlaid buffers
    // are written -- see aliasing audit in gather_gene_chembin_kernel comment
    size_t union_off = off;
    unsigned* records = (unsigned*)(ws_i + union_off);
    unsigned short* agg1b   = (unsigned short*)(ws_i + union_off);
    unsigned short* h_geneb = agg1b + (size_t)N_GENE * IN_D;
    float* agg1f   = (float*)(ws_i + union_off);
    float* h_genef = agg1f + (size_t)N_GENE * IN_D;
    size_t union_sz = (size_t)NB * CAP;                  // 5.77M ints
    if (union_sz < (size_t)N_GENE * (IN_D + HID_D)) union_sz = (size_t)N_GENE * (IN_D + HID_D);
    off = union_off + union_sz;
    unsigned short* Wh2b = (unsigned short*)(ws_i + off); off += (size_t)N_GENE * OUT_D / 2;
    unsigned short* embedb = (unsigned short*)(ws_i + off); off += (size_t)N_CHEM * IN_D / 2;
    unsigned short* W1t = (unsigned short*)(ws_i + off); off += (size_t)HID_D * IN_D / 2;
    unsigned short* W2t = (unsigned short*)(ws_i + off); off += (size_t)OUT_D * HID_D / 2;
    const bool bf16_embed = ws_size >= off * sizeof(int);        // launch-constant

    (void)hipMemsetAsync(bcur, 0, NB * sizeof(int), stream);

    // ---- CSR build + (overlapped) embed conversion + weight transpose
    const int nextra = bf16_embed ? (NCONV + NWT) : 0;
    place_convert_kernel<<<NBA + nextra, 256, 0, stream>>>(
        src_cg, dst_cg, src_gc, dst_gc, bcur, records, embed_chem, embedb,
        W1_cg, W2_gc, W1t, W2t);

    if (bf16_embed) {
        // bin GENE buckets only -- chem binning hides under the gene gather
        bin_b_kernel<<<NGB, 256, 0, stream>>>(records, bcur, istart, iend, esrc);
        // fused: chem bin_b (blocks [0,NCB)) + gene gather-mean (bf16 output)
        gather_gene_chembin_kernel<<<NCB + NGGB, 256, 0, stream>>>(
            embedb, esrc, agg1b, N_GENE, records, bcur, istart, iend, esrc);
        // h_gene(bf16) = deg>0 ? leaky(agg1 @ W1 + b1) : 0   [MFMA, Wt staged]
        {
            dim3 g((N_GENE + 63) / 64, HID_D / 64), blk(256);
            gemm_mfma_kernel<IN_D, HID_D, true><<<g, blk, 0, stream>>>(
                agg1b, W1t, b1_cg, istart, iend, h_geneb, N_GENE);
        }
        // Wh2(bf16) = h_gene @ W2 + b2   [MFMA, Wt staged]
        {
            dim3 g((N_GENE + 63) / 64, OUT_D / 64), blk(256);
            gemm_mfma_kernel<HID_D, OUT_D, false><<<g, blk, 0, stream>>>(
                h_geneb, W2t, b2_gc, istart, iend, Wh2b, N_GENE);
        }
    } else {
        bin_b_kernel<<<NB, 256, 0, stream>>>(records, bcur, istart, iend, esrc);
        gather_mean_f32_kernel<<<(N_GENE + 7) / 8, 256, 0, stream>>>(
            embed_chem, istart, iend, esrc, agg1f, N_GENE);
        {
            dim3 g((N_GENE + 63) / 64, HID_D / 64), blk(256);
            gemm_kernel<IN_D, HID_D, true, false><<<g, blk, 0, stream>>>(
                agg1f, W1_cg, b1_cg, istart, iend, h_genef, N_GENE);
        }
        {
            dim3 g((N_GENE + 63) / 64, OUT_D / 64), blk(256);
            gemm_kernel<HID_D, OUT_D, false, true><<<g, blk, 0, stream>>>(
                h_genef, W2_gc, b2_gc, istart, iend, Wh2b, N_GENE);
        }
    }

    // out = seg_mean(Wh2[src_gc], dst_gc, N_CHEM)  (chem segments start at N_GENE)
    gather_mean_bf16_kernel<true><<<(N_CHEM + 15) / 16, 256, 0, stream>>>(
        Wh2b, istart + N_GENE, iend + N_GENE, esrc, out, N_CHEM);
}